// Round 3
// baseline (694.911 us; speedup 1.0000x reference)
//
#include <hip/hip_runtime.h>

// GRU_27212912787836 : 2-layer GRU, B=512, T=1024, IN=3, H=64 (fp32 in/out)
// bf16 MFMA internally, fp32 cell math/state.
//
// Round 6: one-wave-per-batch-per-layer. 256 blocks x 256 thr; block = 2
// independent batch pipelines, each {L0 wave, L1 wave} (4 waves -> 4 SIMDs).
// The per-step h self-exchange is now INTRA-WAVE: h is written to LDS
// (1 b16/lane), lgkmcnt(0), read back as duplicated-row A-fragments
// (broadcast ds_read_b128, conflict-free). No cross-wave wait on the
// recurrence's critical path. The only inter-wave sync is the L0->L1 ring
// handoff: 2-slot ring + ONE bare s_barrier per round (writes are already
// lgkm-drained at the self-exchange, so the barrier drains nothing).
//
// Duplicated-rows trick: A rows 0..15 all hold the same h vector, so every
// C/D component of every lane equals the matvec for its column; lane
// (grp,c) selects tile grp's comp[0] (cndmask x3 per gate) -> lane l owns
// feature l -> exactly 1 cell-math per lane.
// Zero-C trick: chains start MFMA(a,w,Z) with loop-invariant Z=0 -> no
// per-step accumulator-init movs. L0's x-part (K=3) is 9 scalar FMAs in
// fp32 (no MFMA). Gate scales folded into weights/biases as in round 4/5.

typedef __attribute__((ext_vector_type(8))) short short8;   // 8 bf16
typedef __attribute__((ext_vector_type(4))) float floatx4;  // MFMA C/D

#define MFMA16(a, b, c) __builtin_amdgcn_mfma_f32_16x16x32_bf16((a), (b), (c), 0, 0, 0)

static constexpr int kB = 512;
static constexpr int kT = 1024;
static constexpr int kIN = 3;
static constexpr int kH = 64;
static constexpr float kL2E = 1.44269504f;

__device__ __forceinline__ unsigned short f2bf(float f) {
  unsigned u = __builtin_bit_cast(unsigned, f);
  return (unsigned short)((u + 0x7FFFu + ((u >> 16) & 1u)) >> 16);
}
__device__ __forceinline__ short8 cvt8s(const float* p, float s) {
  short8 f;
#pragma unroll
  for (int j = 0; j < 8; ++j) f[j] = (short)f2bf(p[j] * s);
  return f;
}

__global__ __launch_bounds__(256, 1) void gru_kernel(
    const float* __restrict__ x,
    const float* __restrict__ Wih0, const float* __restrict__ Whh0,
    const float* __restrict__ bih0, const float* __restrict__ bhh0,
    const float* __restrict__ Wih1, const float* __restrict__ Whh1,
    const float* __restrict__ bih1, const float* __restrict__ bhh1,
    float* __restrict__ out) {
  const int tid  = threadIdx.x;
  const int lane = tid & 63;
  const int wid  = tid >> 6;    // 0..3
  const int pipe = wid >> 1;    // batch pipeline 0/1
  const int lyr  = wid & 1;     // 0: layer0 wave, 1: layer1 wave
  const int c    = lane & 15;
  const int grp  = lane >> 4;
  const int f    = lane;        // feature owned by this lane (grp*16+c)
  const int b    = blockIdx.x * 2 + pipe;

  // h0 handoff ring (2 slots) + L1 self-exchange slot, per pipeline.
  __shared__ __align__(16) unsigned short ring[2][2][64];
  __shared__ __align__(16) unsigned short h1s[2][64];

  const float gsc[3] = {-kL2E, -kL2E, 2.0f * kL2E};
  const floatx4 Z = {0.f, 0.f, 0.f, 0.f};

  if (lyr == 0) {
    // ================= LAYER-0 wave (batch b) =================
    short8 wh[3][4][2];  // [gate][N-tile][K-chunk], pre-scaled bf16
#pragma unroll
    for (int g = 0; g < 3; ++g)
#pragma unroll
      for (int tq = 0; tq < 4; ++tq)
#pragma unroll
        for (int k = 0; k < 2; ++k)
          wh[g][tq][k] = cvt8s(Whh0 + ((g * 4 + tq) * 16 + c) * kH + k * 32 + grp * 8, gsc[g]);

    float wx[3][3];  // x-part weights, fp32, scaled
#pragma unroll
    for (int g = 0; g < 3; ++g)
#pragma unroll
      for (int i = 0; i < 3; ++i) wx[g][i] = Wih0[(g * kH + f) * kIN + i] * gsc[g];
    const float bxr = gsc[0] * (bih0[f] + bhh0[f]);
    const float bxz = gsc[1] * (bih0[64 + f] + bhh0[64 + f]);
    const float bxn = gsc[2] * bih0[128 + f];
    const float bnh = gsc[2] * bhh0[128 + f];

    // x pipeline: gx holds step t's x-part; nx holds x(t+1) raw.
    const float* xb = x + (size_t)b * kT * kIN;
    float cx0 = xb[0], cx1 = xb[1], cx2 = xb[2];
    float gxr = fmaf(wx[0][0], cx0, fmaf(wx[0][1], cx1, fmaf(wx[0][2], cx2, bxr)));
    float gxz = fmaf(wx[1][0], cx0, fmaf(wx[1][1], cx1, fmaf(wx[1][2], cx2, bxz)));
    float gxn = fmaf(wx[2][0], cx0, fmaf(wx[2][1], cx1, fmaf(wx[2][2], cx2, bxn)));
    float nx0 = 0.f, nx1 = 0.f, nx2 = 0.f;
    if (kT > 1) { nx0 = xb[3]; nx1 = xb[4]; nx2 = xb[5]; }

    short8 a0 = {0, 0, 0, 0, 0, 0, 0, 0}, a1 = a0;  // h0(t-1) dup-row A-frags
    float hp = 0.f;

#pragma unroll 1
    for (int t = 0; t <= kT; ++t) {
      if (t < kT) {
        floatx4 aR[4], aZ[4], aN[4];
#pragma unroll
        for (int tq = 0; tq < 4; ++tq) {
          aR[tq] = MFMA16(a0, wh[0][tq][0], Z); aR[tq] = MFMA16(a1, wh[0][tq][1], aR[tq]);
          aZ[tq] = MFMA16(a0, wh[1][tq][0], Z); aZ[tq] = MFMA16(a1, wh[1][tq][1], aZ[tq]);
          aN[tq] = MFMA16(a0, wh[2][tq][0], Z); aN[tq] = MFMA16(a1, wh[2][tq][1], aN[tq]);
        }
        // lane (grp,c) owns feature grp*16+c -> take tile grp's comp[0]
        float sr = grp == 0 ? aR[0][0] : grp == 1 ? aR[1][0] : grp == 2 ? aR[2][0] : aR[3][0];
        float sz = grp == 0 ? aZ[0][0] : grp == 1 ? aZ[1][0] : grp == 2 ? aZ[2][0] : aZ[3][0];
        float sn = grp == 0 ? aN[0][0] : grp == 1 ? aN[1][0] : grp == 2 ? aN[2][0] : aN[3][0];

        float ar = sr + gxr, az = sz + gxz;
        float anx = gxn, anh = sn + bnh;
        float r_ = __builtin_amdgcn_rcpf(1.0f + __builtin_amdgcn_exp2f(ar));
        float z_ = __builtin_amdgcn_rcpf(1.0f + __builtin_amdgcn_exp2f(az));
        float u  = __builtin_amdgcn_rcpf(1.0f + __builtin_amdgcn_exp2f(anx + r_ * anh));
        float ng = 1.0f - 2.0f * u;
        float hn = ng + z_ * (hp - ng);
        hp = hn;

        // intra-wave self-exchange + publish to L1 (same data)
        unsigned short* slot = &ring[pipe][t & 1][0];
        slot[f] = f2bf(hn);
        asm volatile("s_waitcnt lgkmcnt(0)" ::: "memory");  // cross-lane visibility
        a0 = *(const short8*)(slot + grp * 8);        // feats grp*8..+7 (broadcast)
        a1 = *(const short8*)(slot + 32 + grp * 8);   // feats 32+grp*8..+7

        // off-path tail: x-part for t+1, then prefetch x(t+2)
        if (t + 1 < kT) {
          gxr = fmaf(wx[0][0], nx0, fmaf(wx[0][1], nx1, fmaf(wx[0][2], nx2, bxr)));
          gxz = fmaf(wx[1][0], nx0, fmaf(wx[1][1], nx1, fmaf(wx[1][2], nx2, bxz)));
          gxn = fmaf(wx[2][0], nx0, fmaf(wx[2][1], nx1, fmaf(wx[2][2], nx2, bxn)));
          if (t + 2 < kT) {
            const float* p = xb + (size_t)(t + 2) * kIN;
            nx0 = p[0]; nx1 = p[1]; nx2 = p[2];
          }
        }
      }
      asm volatile("s_barrier" ::: "memory");  // bare: writes already drained
    }
  } else {
    // ================= LAYER-1 wave (batch b, lags one round) =================
    short8 wi[3][4][2], wh[3][4][2];
#pragma unroll
    for (int g = 0; g < 3; ++g)
#pragma unroll
      for (int tq = 0; tq < 4; ++tq)
#pragma unroll
        for (int k = 0; k < 2; ++k) {
          const int off = ((g * 4 + tq) * 16 + c) * kH + k * 32 + grp * 8;
          wi[g][tq][k] = cvt8s(Wih1 + off, gsc[g]);
          wh[g][tq][k] = cvt8s(Whh1 + off, gsc[g]);
        }
    const float br  = gsc[0] * (bih1[f] + bhh1[f]);
    const float bz  = gsc[1] * (bih1[64 + f] + bhh1[64 + f]);
    const float bnx = gsc[2] * bih1[128 + f];
    const float bnh = gsc[2] * bhh1[128 + f];

    short8 h1a0 = {0, 0, 0, 0, 0, 0, 0, 0}, h1a1 = h1a0;
    float hp = 0.f;
    float* ob = out + (size_t)b * kT * kH + f;
    const size_t FH = (size_t)kB * kT * kH;

#pragma unroll 1
    for (int t = 0; t <= kT; ++t) {
      if (t >= 1) {
        // h0(t-1): published before the previous barrier; issue reads first
        const unsigned short* s0 = &ring[pipe][(t - 1) & 1][0];
        short8 x0 = *(const short8*)(s0 + grp * 8);
        short8 x1 = *(const short8*)(s0 + 32 + grp * 8);

        floatx4 aR[4], aZ[4], aNH[4], aNX[4];
        // self links first (register operands) -- covers the s0 read latency
#pragma unroll
        for (int tq = 0; tq < 4; ++tq) {
          aR[tq]  = MFMA16(h1a0, wh[0][tq][0], Z); aR[tq]  = MFMA16(h1a1, wh[0][tq][1], aR[tq]);
          aZ[tq]  = MFMA16(h1a0, wh[1][tq][0], Z); aZ[tq]  = MFMA16(h1a1, wh[1][tq][1], aZ[tq]);
          aNH[tq] = MFMA16(h1a0, wh[2][tq][0], Z); aNH[tq] = MFMA16(h1a1, wh[2][tq][1], aNH[tq]);
        }
#pragma unroll
        for (int tq = 0; tq < 4; ++tq) {
          aR[tq]  = MFMA16(x0, wi[0][tq][0], aR[tq]);  aR[tq]  = MFMA16(x1, wi[0][tq][1], aR[tq]);
          aZ[tq]  = MFMA16(x0, wi[1][tq][0], aZ[tq]);  aZ[tq]  = MFMA16(x1, wi[1][tq][1], aZ[tq]);
          aNX[tq] = MFMA16(x0, wi[2][tq][0], Z);       aNX[tq] = MFMA16(x1, wi[2][tq][1], aNX[tq]);
        }
        float sr  = grp == 0 ? aR[0][0]  : grp == 1 ? aR[1][0]  : grp == 2 ? aR[2][0]  : aR[3][0];
        float sz  = grp == 0 ? aZ[0][0]  : grp == 1 ? aZ[1][0]  : grp == 2 ? aZ[2][0]  : aZ[3][0];
        float snh = grp == 0 ? aNH[0][0] : grp == 1 ? aNH[1][0] : grp == 2 ? aNH[2][0] : aNH[3][0];
        float snx = grp == 0 ? aNX[0][0] : grp == 1 ? aNX[1][0] : grp == 2 ? aNX[2][0] : aNX[3][0];

        float ar = sr + br, az = sz + bz;
        float anx = snx + bnx, anh = snh + bnh;
        float r_ = __builtin_amdgcn_rcpf(1.0f + __builtin_amdgcn_exp2f(ar));
        float z_ = __builtin_amdgcn_rcpf(1.0f + __builtin_amdgcn_exp2f(az));
        float u  = __builtin_amdgcn_rcpf(1.0f + __builtin_amdgcn_exp2f(anx + r_ * anh));
        float ng = 1.0f - 2.0f * u;
        float hn = ng + z_ * (hp - ng);
        hp = hn;

        // seq_out straight from registers; stores stay in flight (no vmcnt drain)
        ob[(size_t)(t - 1) * kH] = hn;
        if (t == kT) out[FH + (size_t)b * kH + f] = hn;

        // intra-wave self-exchange (single slot: same-wave in-order)
        unsigned short* s1 = &h1s[pipe][0];
        s1[f] = f2bf(hn);
        asm volatile("s_waitcnt lgkmcnt(0)" ::: "memory");
        h1a0 = *(const short8*)(s1 + grp * 8);
        h1a1 = *(const short8*)(s1 + 32 + grp * 8);
      }
      asm volatile("s_barrier" ::: "memory");
    }
  }
}

extern "C" void kernel_launch(void* const* d_in, const int* in_sizes, int n_in,
                              void* d_out, int out_size, void* d_ws, size_t ws_size,
                              hipStream_t stream) {
  const float* xp   = (const float*)d_in[0];
  const float* wih0 = (const float*)d_in[1];
  const float* whh0 = (const float*)d_in[2];
  const float* bih0 = (const float*)d_in[3];
  const float* bhh0 = (const float*)d_in[4];
  const float* wih1 = (const float*)d_in[5];
  const float* whh1 = (const float*)d_in[6];
  const float* bih1 = (const float*)d_in[7];
  const float* bhh1 = (const float*)d_in[8];
  float* outp = (float*)d_out;
  hipLaunchKernelGGL(gru_kernel, dim3(kB / 2), dim3(256), 0, stream,
                     xp, wih0, whh0, bih0, bhh0, wih1, whh1, bih1, bhh1, outp);
}